// Round 3
// baseline (347.695 us; speedup 1.0000x reference)
//
#include <hip/hip_runtime.h>
#include <cstdint>
#include <cstddef>

#define NEG_SLOPE 0.2f

typedef short bf16x8 __attribute__((ext_vector_type(8)));
typedef float f32x4 __attribute__((ext_vector_type(4)));
typedef float f32x2 __attribute__((ext_vector_type(2)));

__device__ __forceinline__ unsigned short f2bf(float f) {
  unsigned u = __float_as_uint(f);
  u = u + 0x7FFFu + ((u >> 16) & 1u);
  return (unsigned short)(u >> 16);
}
__device__ __forceinline__ float bf2f(unsigned short b) {
  return __uint_as_float((unsigned)b << 16);
}
__device__ __forceinline__ f32x2 unpk(unsigned xv) {
  f32x2 r;
  r.x = __uint_as_float(xv << 16);
  r.y = __uint_as_float(xv & 0xFFFF0000u);
  return r;
}
// wave-uniform broadcast of lane l's float (l compile-time or SGPR)
__device__ __forceinline__ float rlf(float v, int l) {
  return __uint_as_float(
      (unsigned)__builtin_amdgcn_readlane((int)__float_as_uint(v), l));
}
// async global->LDS DMA, 16 B/lane: 64 lanes x 16 B = 1 KiB per inst.
__device__ __forceinline__ void dma16(const unsigned short* g, unsigned short* l) {
  __builtin_amdgcn_global_load_lds(
      (const __attribute__((address_space(1))) unsigned*)g,
      (__attribute__((address_space(3))) unsigned*)l, 16, 0, 0);
}
// async global->LDS DMA, 4 B/lane: 64 lanes x 4 B = 256 B per inst.
__device__ __forceinline__ void dma4(const unsigned short* g, unsigned short* l) {
  __builtin_amdgcn_global_load_lds(
      (const __attribute__((address_space(1))) unsigned*)g,
      (__attribute__((address_space(3))) unsigned*)l, 4, 0, 0);
}

// ======================================================================
// P1: all independent prep, partitioned by blockIdx.
// ======================================================================
__global__ __launch_bounds__(256) void prep_all(
    const int* __restrict__ ei, int* __restrict__ counts,
    const float* __restrict__ x, unsigned short* __restrict__ xb,
    const float* __restrict__ W1, const float* __restrict__ att_s1,
    const float* __restrict__ att_d1, unsigned short* __restrict__ AsAdT,
    unsigned short* __restrict__ WbT,
    const float* __restrict__ W2, unsigned short* __restrict__ W2t,
    const float* __restrict__ att_s2, const float* __restrict__ att_d2,
    float* __restrict__ AsAd2,
    int E, int ET, int N, int B0, int B1) {
  int b = blockIdx.x, tid = threadIdx.x;
  if (b < B0) {  // count_dst
    int i = b * 256 + tid;
    if (i < ET) {
      int dst = (i < E) ? ei[E + i] : (i - E);
      atomicAdd(&counts[dst], 1);
    }
    return;
  }
  b -= B0;
  if (b < B1) {  // cast x -> xb
    int i = b * 256 + tid;
    if (i < N * 32) {
      float4 v = ((const float4*)x)[i];
      ushort4 o;
      o.x = f2bf(v.x); o.y = f2bf(v.y); o.z = f2bf(v.z); o.w = f2bf(v.w);
      ((ushort4*)xb)[i] = o;
    }
    return;
  }
  b -= B1;
  if (b < 8) {  // AsAdT[16][128]
    int i = b * 256 + tid;
    int o = i >> 7, k = i & 127, h = o & 7;
    const float* att = (o < 8) ? att_s1 : att_d1;
    float s = 0.f;
    for (int c = 0; c < 64; c++) s += W1[(size_t)k * 512 + h * 64 + c] * att[h * 64 + c];
    AsAdT[i] = f2bf(s);
    return;
  }
  b -= 8;
  if (b < 256) {  // WbT[64][1024]: WbT[o][h*128+c] = W1[c][h*64+o]
    int i = b * 256 + tid;
    int o = i >> 10, k = i & 1023, h = k >> 7, c = k & 127;
    WbT[i] = f2bf(W1[(size_t)c * 512 + h * 64 + o]);
    return;
  }
  b -= 256;
  if (b < 16) {  // W2t[64][64]: W2t[nn][k] = W2[k][nn]
    int i = b * 256 + tid;
    if (i < 64 * 64) {
      int k = i >> 6, nn = i & 63;
      W2t[(size_t)nn * 64 + k] = f2bf(W2[i]);
    }
    return;
  }
  // AsAd2[2][64]
  {
    int i = tid;
    if (i < 128) {
      int o = i >> 6, k = i & 63;
      const float* att = (o == 0) ? att_s2 : att_d2;
      float s = 0.f;
      for (int c = 0; c < 64; c++) s += W2[(size_t)k * 64 + c] * att[c];
      AsAd2[i] = s;
    }
  }
}

// ======================================================================
// P2: block 0 = single-block scan; blocks 1.. = layer-1 attention dots.
// ======================================================================
__global__ __launch_bounds__(1024) void scan_dots(
    const int* __restrict__ counts, int* __restrict__ offsets,
    const unsigned short* __restrict__ xb, const unsigned short* __restrict__ AsAdT,
    float* __restrict__ asd, int n) {
  if (blockIdx.x == 0) {
    __shared__ int sums[1024];
    int t = threadIdx.x;
    int chunk = (n + 1023) >> 10;
    int start = t * chunk;
    int end = min(start + chunk, n);
    int s = 0;
    for (int i = start; i < end; i++) s += counts[i];
    sums[t] = s;
    __syncthreads();
    for (int off = 1; off < 1024; off <<= 1) {
      int v = (t >= off) ? sums[t - off] : 0;
      __syncthreads();
      sums[t] += v;
      __syncthreads();
    }
    int run = sums[t] - s;
    for (int i = start; i < end; i++) { offsets[i] = run; run += counts[i]; }
    if (t == 1023) offsets[n] = sums[1023];
    return;
  }
  int tid = threadIdx.x;
  int wave = tid >> 6, lane = tid & 63;
  int q = lane >> 4, t = lane & 15;
  int row0 = (blockIdx.x - 1) * 256 + wave * 16;
  int arow = row0 + t; if (arow > n - 1) arow = n - 1;
  const bf16x8* aptr = (const bf16x8*)(xb + (size_t)arow * 128);
  const bf16x8* bptr = (const bf16x8*)(AsAdT + t * 128);
  f32x4 acc = (f32x4){0.f, 0.f, 0.f, 0.f};
  #pragma unroll
  for (int s = 0; s < 4; s++)
    acc = __builtin_amdgcn_mfma_f32_16x16x32_bf16(aptr[s * 4 + q], bptr[s * 4 + q],
                                                  acc, 0, 0, 0);
  #pragma unroll
  for (int r = 0; r < 4; r++) {
    int row = row0 + q * 4 + r;
    if (row < n) asd[row * 16 + t] = acc[r];
  }
}

// ======================================================================
// P3: pure CSR fill (numerators computed inside agg kernels from asd).
// ======================================================================
__global__ __launch_bounds__(256) void fill_csr(
    const int* __restrict__ ei, const int* __restrict__ offsets,
    int* __restrict__ cursor, int* __restrict__ srcs, int E, int ET) {
  int i = blockIdx.x * 256 + threadIdx.x;
  if (i >= ET) return;
  int src, dst;
  if (i < E) { src = ei[i]; dst = ei[E + i]; } else { src = dst = i - E; }
  int pos = atomicAdd(&cursor[dst], 1);
  srcs[offsets[dst] + pos] = src;
}

// ======================================================================
// P4: fused layer-1 aggregation + GEMM + layer-2 dots. 16 nodes/block,
// wave per node.  EXACT-volume staging: one dma4 (256B = 1 xb row) per
// real edge under a wave-uniform guard -- no padded duplicate rows
// (staged rows 620k -> 458k; the gather path is MSHR/volume-bound).
// Stage zero-initialized once per wave so padded consume slots are 0*0.
// Weights from asd[src] gather, readlane broadcast, zero-padded;
// per-lane softmax denominator.
// ======================================================================
__global__ __launch_bounds__(1024, 8) void agg1_gemm(
    const int* __restrict__ offsets, const int* __restrict__ srcs,
    const float* __restrict__ asd, const unsigned short* __restrict__ xb,
    const unsigned short* __restrict__ WbT, const float* __restrict__ b1,
    const float* __restrict__ AsAd2, unsigned short* __restrict__ zb,
    float* __restrict__ as2, float* __restrict__ ad2, int N) {
  // 16 waves x 16 rows x 256B stage = 64 KiB; first 16*1032 ushorts
  // reused as the z-tile (stride 1032 keeps the MFMA reads conflict-free)
  __shared__ unsigned short sh[16 * 2048];
  int tid = threadIdx.x;
  int wv = tid >> 6, lane = tid & 63;
  int nb = blockIdx.x;
  {
    int node = nb * 16 + wv;
    unsigned short* stg = &sh[wv * 2048];
    // zero-init stage (4 KiB) so padded slots read as 0.0 (w=0 anyway)
    #pragma unroll
    for (int z = 0; z < 4; z++)
      ((f32x4*)stg)[z * 64 + lane] = (f32x4){0.f, 0.f, 0.f, 0.f};
    __builtin_amdgcn_s_waitcnt(0xC07F);   // lgkmcnt(0): zeros landed
    f32x2 acc[8];
    #pragma unroll
    for (int h = 0; h < 8; h++) acc[h] = (f32x2){0.f, 0.f};
    float wsl = 0.f;
    int beg = offsets[node], end = offsets[node + 1];
    int jl = end - 1;                       // deg >= 1 (self-loop)
    float adv = asd[(size_t)node * 16 + 8 + (lane & 7)];  // dst dots (uniform row)
    for (int cb = beg; cb < end; cb += 16) {
      int cnt = min(16, end - cb);
      // srcs for this chunk: lane&15 = edge index (also used by readlane)
      int sAll = srcs[min(cb + (lane & 15), jl)];
      int swa = srcs[min(cb + (lane >> 3), jl)];
      int swb = srcs[min(cb + 8 + (lane >> 3), jl)];
      float asva = asd[(size_t)swa * 16 + (lane & 7)];
      float asvb = asd[(size_t)swb * 16 + (lane & 7)];
      // exact-row DMAs: one dma4 (64 lanes x 4B = 256B row) per real edge
      #pragma unroll
      for (int k = 0; k < 16; k++) {
        if (k < cnt) {
          int se = __builtin_amdgcn_readlane(sAll, k);
          dma4(xb + (size_t)(unsigned)se * 128 + 2 * lane, stg + k * 128);
        }
      }
      // weights (lane = edge*8+head layout), zero-padded
      float wa, wb = 0.f;
      {
        float v = asva + adv;
        v = (v > 0.f) ? v : NEG_SLOPE * v;
        wa = (cb + (lane >> 3) < end) ? __expf(v) : 0.f;
      }
      if (cnt > 8) {
        float v = asvb + adv;
        v = (v > 0.f) ? v : NEG_SLOPE * v;
        wb = (cb + 8 + (lane >> 3) < end) ? __expf(v) : 0.f;
      }
      wsl += wa + wb;                       // per-lane denominator partial
      __builtin_amdgcn_s_waitcnt(0x0f70);   // vmcnt(0): DMA rows landed
      // consume edges 0-7 (readlane broadcasts, all lanes active)
      #pragma unroll
      for (int k = 0; k < 8; k++) {
        unsigned xv = *(const unsigned*)&stg[k * 128 + 2 * lane];
        f32x2 x2 = unpk(xv);
        acc[0] += x2 * rlf(wa, k * 8 + 0);
        acc[1] += x2 * rlf(wa, k * 8 + 1);
        acc[2] += x2 * rlf(wa, k * 8 + 2);
        acc[3] += x2 * rlf(wa, k * 8 + 3);
        acc[4] += x2 * rlf(wa, k * 8 + 4);
        acc[5] += x2 * rlf(wa, k * 8 + 5);
        acc[6] += x2 * rlf(wa, k * 8 + 6);
        acc[7] += x2 * rlf(wa, k * 8 + 7);
      }
      if (cnt > 8) {  // edges 8-15
        #pragma unroll
        for (int k = 0; k < 8; k++) {
          unsigned xv = *(const unsigned*)&stg[1024 + k * 128 + 2 * lane];
          f32x2 x2 = unpk(xv);
          acc[0] += x2 * rlf(wb, k * 8 + 0);
          acc[1] += x2 * rlf(wb, k * 8 + 1);
          acc[2] += x2 * rlf(wb, k * 8 + 2);
          acc[3] += x2 * rlf(wb, k * 8 + 3);
          acc[4] += x2 * rlf(wb, k * 8 + 4);
          acc[5] += x2 * rlf(wb, k * 8 + 5);
          acc[6] += x2 * rlf(wb, k * 8 + 6);
          acc[7] += x2 * rlf(wb, k * 8 + 7);
        }
      }
    }
    // denominator: sum the 8 lanes sharing (lane&7); lane h then holds ws[h]
    wsl += __shfl_xor(wsl, 8, 64);
    wsl += __shfl_xor(wsl, 16, 64);
    wsl += __shfl_xor(wsl, 32, 64);
    __syncthreads();   // all waves done reading their stage region
    #pragma unroll
    for (int h = 0; h < 8; h++) {
      float tot = rlf(wsl, h);
      float iv = 0.125f / tot;  // head-mean folded in
      unsigned o = (unsigned)f2bf(acc[h].x * iv) | ((unsigned)f2bf(acc[h].y * iv) << 16);
      *(unsigned*)&sh[wv * 1032 + h * 128 + 2 * lane] = o;
    }
  }
  __syncthreads();
  if (wv < 4) {
    int q = lane >> 4, t = lane & 15;
    f32x4 acc4 = (f32x4){0.f, 0.f, 0.f, 0.f};
    const unsigned short* bbase = WbT + (size_t)(wv * 16 + t) * 1024;
    #pragma unroll 8
    for (int s = 0; s < 32; s++) {
      bf16x8 af = *(const bf16x8*)&sh[t * 1032 + s * 32 + q * 8];
      bf16x8 bf = *(const bf16x8*)&bbase[s * 32 + q * 8];
      acc4 = __builtin_amdgcn_mfma_f32_16x16x32_bf16(af, bf, acc4, 0, 0, 0);
    }
    int col = wv * 16 + t;
    float bias = b1[col];
    float vs = AsAd2[col], vd = AsAd2[64 + col];
    #pragma unroll
    for (int r = 0; r < 4; r++) {
      int row = q * 4 + r;
      int node = nb * 16 + row;
      float v = acc4[r] + bias;
      v = (v > 0.f) ? v : (__expf(v) - 1.f);  // ELU
      zb[(size_t)node * 64 + col] = f2bf(v);
      float s = v * vs, d = v * vd;
      #pragma unroll
      for (int off = 1; off < 16; off <<= 1) {
        s += __shfl_xor(s, off, 64);
        d += __shfl_xor(d, off, 64);
      }
      if (t == 0) {
        atomicAdd(&as2[node], s);
        atomicAdd(&ad2[node], d);
      }
    }
  }
}

// ======================================================================
// P5: fused layer-2 aggregation + GEMM(W2) + bias -> out.
// 16 nodes/block, wave per node, 16-edge chunks.  EXACT-volume staging:
// one dma4 = 2 zb rows (128B each) per instruction, ceil(deg/2) pairs,
// no 16-row padding.  Stage zero-initialized once per wave.
// ======================================================================
__global__ __launch_bounds__(1024, 8) void agg2_gemm(
    const int* __restrict__ offsets, const int* __restrict__ srcs,
    const float* __restrict__ as2, const float* __restrict__ ad2,
    const unsigned short* __restrict__ zb, const unsigned short* __restrict__ W2t,
    const float* __restrict__ b2, float* __restrict__ out, int N) {
  __shared__ unsigned short stg[16 * 1024];  // 16 waves x (16 edges x 128B)
  __shared__ unsigned short sh[16 * 72];
  int tid = threadIdx.x;
  int wv = tid >> 6, lane = tid & 63;
  int nb = blockIdx.x;
  {
    int node = nb * 16 + wv;
    unsigned short* st = &stg[wv * 1024];
    // zero-init stage (2 KiB)
    #pragma unroll
    for (int z = 0; z < 2; z++)
      ((f32x4*)st)[z * 64 + lane] = (f32x4){0.f, 0.f, 0.f, 0.f};
    __builtin_amdgcn_s_waitcnt(0xC07F);      // lgkmcnt(0)
    float adv = ad2[node];
    int beg = offsets[node], end = offsets[node + 1];
    int jl = end - 1;                        // deg >= 1 (self-loop)
    f32x2 acc = (f32x2){0.f, 0.f};
    float wsl = 0.f;
    for (int cb = beg; cb < end; cb += 16) {
      int cnt = min(16, end - cb);
      int sAll = srcs[min(cb + (lane & 15), jl)];
      float asv = as2[sAll];                 // weight source (lane&15 = edge)
      // exact staging: dma4 = rows 2k (lanes<32) and 2k+1 (lanes>=32)
      #pragma unroll
      for (int k = 0; k < 8; k++) {
        if (2 * k < cnt) {
          int sa = __builtin_amdgcn_readlane(sAll, 2 * k);
          int sb = __builtin_amdgcn_readlane(sAll, 2 * k + 1);
          int se = (lane >= 32) ? sb : sa;
          dma4(zb + (size_t)(unsigned)se * 64 + 2 * (lane & 31), st + k * 128);
        }
      }
      float v = asv + adv;
      v = (v > 0.f) ? v : NEG_SLOPE * v;
      float wl = (cb + (lane & 15) < end) ? __expf(v) : 0.f;
      if (lane < 16) wsl += wl;              // each edge counted once
      __builtin_amdgcn_s_waitcnt(0x0f70);    // vmcnt(0): rows landed
      // consume 2 edges/iter: lanes<32 -> even edge, lanes>=32 -> odd edge
      #pragma unroll
      for (int k = 0; k < 4; k++) {
        float w0 = rlf(wl, 2 * k);
        float w1 = rlf(wl, 2 * k + 1);
        float w = (lane >= 32) ? w1 : w0;
        unsigned zv = *(const unsigned*)&st[k * 128 + 2 * lane];
        acc += unpk(zv) * w;
      }
      if (cnt > 8) {
        #pragma unroll
        for (int k = 4; k < 8; k++) {
          float w0 = rlf(wl, 2 * k);
          float w1 = rlf(wl, 2 * k + 1);
          float w = (lane >= 32) ? w1 : w0;
          unsigned zv = *(const unsigned*)&st[k * 128 + 2 * lane];
          acc += unpk(zv) * w;
        }
      }
    }
    // denominator: total over edges (held in lanes 0-15)
    wsl += __shfl_xor(wsl, 1, 64);
    wsl += __shfl_xor(wsl, 2, 64);
    wsl += __shfl_xor(wsl, 4, 64);
    wsl += __shfl_xor(wsl, 8, 64);
    float tot = rlf(wsl, 0);
    // fold odd-edge half into even half
    acc.x += __shfl_xor(acc.x, 32, 64);
    acc.y += __shfl_xor(acc.y, 32, 64);
    if (lane < 32) {
      float inv = 1.f / tot;
      unsigned o = (unsigned)f2bf(acc.x * inv) | ((unsigned)f2bf(acc.y * inv) << 16);
      *(unsigned*)&sh[wv * 72 + 2 * lane] = o;
    }
  }
  __syncthreads();
  if (wv < 4) {
    int q = lane >> 4, t = lane & 15;
    f32x4 acc4 = (f32x4){0.f, 0.f, 0.f, 0.f};
    const unsigned short* bbase = W2t + (size_t)(wv * 16 + t) * 64;
    #pragma unroll
    for (int s = 0; s < 2; s++) {
      bf16x8 af = *(const bf16x8*)&sh[t * 72 + s * 32 + q * 8];
      bf16x8 bf = *(const bf16x8*)&bbase[s * 32 + q * 8];
      acc4 = __builtin_amdgcn_mfma_f32_16x16x32_bf16(af, bf, acc4, 0, 0, 0);
    }
    int col = wv * 16 + t;
    float bias = b2[col];
    #pragma unroll
    for (int r = 0; r < 4; r++) {
      int node = nb * 16 + q * 4 + r;
      if (node < N) out[(size_t)node * 64 + col] = acc4[r] + bias;
    }
  }
}

// ---------- host launch ----------
extern "C" void kernel_launch(void* const* d_in, const int* in_sizes, int n_in,
                              void* d_out, int out_size, void* d_ws, size_t ws_size,
                              hipStream_t stream) {
  const int IN = 128;
  const int N = in_sizes[0] / IN;      // 50000
  const int E = in_sizes[1] / 2;       // 400000
  const int ET = E + N;

  const float* x        = (const float*)d_in[0];
  const int*   ei       = (const int*)d_in[1];
  const float* W1       = (const float*)d_in[2];
  const float* att_src1 = (const float*)d_in[3];
  const float* att_dst1 = (const float*)d_in[4];
  const float* b1       = (const float*)d_in[5];
  const float* W2       = (const float*)d_in[6];
  const float* att_src2 = (const float*)d_in[7];
  const float* att_dst2 = (const float*)d_in[8];
  const float* b2       = (const float*)d_in[9];
  float* out = (float*)d_out;

  char* base = (char*)d_ws;
  size_t off = 0;
  auto alloc = [&](size_t bytes) -> char* {
    char* p = base + off;
    off = (off + bytes + 255) & ~(size_t)255;
    return p;
  };
  unsigned short* xb    = (unsigned short*)alloc((size_t)N * 128 * 2);
  unsigned short* AsAdT = (unsigned short*)alloc((size_t)16 * 128 * 2);
  unsigned short* WbT   = (unsigned short*)alloc((size_t)64 * 1024 * 2);
  unsigned short* W2t   = (unsigned short*)alloc((size_t)64 * 64 * 2);
  unsigned short* zb    = (unsigned short*)alloc((size_t)N * 64 * 2);
  float* AsAd2 = (float*)alloc((size_t)128 * 4);
  float* asd1  = (float*)alloc((size_t)N * 16 * 4);
  int* offsets = (int*)alloc((size_t)(N + 1) * 4);
  int* srcs    = (int*)alloc((size_t)ET * 4);
  char* zero_begin = base + off;
  int* counts  = (int*)alloc((size_t)N * 4);
  int* cursor  = (int*)alloc((size_t)N * 4);
  float* a_s2  = (float*)alloc((size_t)N * 4);
  float* a_d2  = (float*)alloc((size_t)N * 4);
  char* zero_end = base + off;

  hipMemsetAsync(zero_begin, 0, (size_t)(zero_end - zero_begin), stream);

  const int TB = 256;
  auto cdiv = [](int a, int b) { return (a + b - 1) / b; };

  int B0 = cdiv(ET, TB);
  int B1 = cdiv(N * 32, TB);
  prep_all<<<B0 + B1 + 8 + 256 + 16 + 1, TB, 0, stream>>>(
      ei, counts, x, xb, W1, att_src1, att_dst1, AsAdT, WbT, W2, W2t,
      att_src2, att_dst2, AsAd2, E, ET, N, B0, B1);

  scan_dots<<<1 + cdiv(N, 256), 1024, 0, stream>>>(counts, offsets, xb, AsAdT,
                                                   asd1, N);

  fill_csr<<<cdiv(ET, TB), TB, 0, stream>>>(ei, offsets, cursor, srcs, E, ET);

  agg1_gemm<<<cdiv(N, 16), 1024, 0, stream>>>(offsets, srcs, asd1, xb, WbT, b1,
                                              AsAd2, zb, a_s2, a_d2, N);

  agg2_gemm<<<cdiv(N, 16), 1024, 0, stream>>>(offsets, srcs, a_s2, a_d2, zb,
                                              W2t, b2, out, N);
}

// Round 4
// 327.238 us; speedup vs baseline: 1.0625x; 1.0625x over previous
//
#include <hip/hip_runtime.h>
#include <cstdint>
#include <cstddef>

#define NEG_SLOPE 0.2f

typedef short bf16x8 __attribute__((ext_vector_type(8)));
typedef float f32x4 __attribute__((ext_vector_type(4)));
typedef float f32x2 __attribute__((ext_vector_type(2)));

__device__ __forceinline__ unsigned short f2bf(float f) {
  unsigned u = __float_as_uint(f);
  u = u + 0x7FFFu + ((u >> 16) & 1u);
  return (unsigned short)(u >> 16);
}
__device__ __forceinline__ float bf2f(unsigned short b) {
  return __uint_as_float((unsigned)b << 16);
}
__device__ __forceinline__ f32x2 unpk(unsigned xv) {
  f32x2 r;
  r.x = __uint_as_float(xv << 16);
  r.y = __uint_as_float(xv & 0xFFFF0000u);
  return r;
}
// wave-uniform broadcast of lane l's float (l compile-time or SGPR)
__device__ __forceinline__ float rlf(float v, int l) {
  return __uint_as_float(
      (unsigned)__builtin_amdgcn_readlane((int)__float_as_uint(v), l));
}
// async global->LDS DMA, 16 B/lane: 64 lanes x 16 B = 1 KiB per inst.
__device__ __forceinline__ void dma16(const unsigned short* g, unsigned short* l) {
  __builtin_amdgcn_global_load_lds(
      (const __attribute__((address_space(1))) unsigned*)g,
      (__attribute__((address_space(3))) unsigned*)l, 16, 0, 0);
}

// ======================================================================
// P1: all independent prep, partitioned by blockIdx.
// ======================================================================
__global__ __launch_bounds__(256) void prep_all(
    const int* __restrict__ ei, int* __restrict__ counts,
    const float* __restrict__ x, unsigned short* __restrict__ xb,
    const float* __restrict__ W1, const float* __restrict__ att_s1,
    const float* __restrict__ att_d1, unsigned short* __restrict__ AsAdT,
    unsigned short* __restrict__ WbT,
    const float* __restrict__ W2, unsigned short* __restrict__ W2t,
    const float* __restrict__ att_s2, const float* __restrict__ att_d2,
    float* __restrict__ AsAd2,
    int E, int ET, int N, int B0, int B1) {
  int b = blockIdx.x, tid = threadIdx.x;
  if (b < B0) {  // count_dst
    int i = b * 256 + tid;
    if (i < ET) {
      int dst = (i < E) ? ei[E + i] : (i - E);
      atomicAdd(&counts[dst], 1);
    }
    return;
  }
  b -= B0;
  if (b < B1) {  // cast x -> xb
    int i = b * 256 + tid;
    if (i < N * 32) {
      float4 v = ((const float4*)x)[i];
      ushort4 o;
      o.x = f2bf(v.x); o.y = f2bf(v.y); o.z = f2bf(v.z); o.w = f2bf(v.w);
      ((ushort4*)xb)[i] = o;
    }
    return;
  }
  b -= B1;
  if (b < 8) {  // AsAdT[16][128]
    int i = b * 256 + tid;
    int o = i >> 7, k = i & 127, h = o & 7;
    const float* att = (o < 8) ? att_s1 : att_d1;
    float s = 0.f;
    for (int c = 0; c < 64; c++) s += W1[(size_t)k * 512 + h * 64 + c] * att[h * 64 + c];
    AsAdT[i] = f2bf(s);
    return;
  }
  b -= 8;
  if (b < 256) {  // WbT[64][1024]: WbT[o][h*128+c] = W1[c][h*64+o]
    int i = b * 256 + tid;
    int o = i >> 10, k = i & 1023, h = k >> 7, c = k & 127;
    WbT[i] = f2bf(W1[(size_t)c * 512 + h * 64 + o]);
    return;
  }
  b -= 256;
  if (b < 16) {  // W2t[64][64]: W2t[nn][k] = W2[k][nn]
    int i = b * 256 + tid;
    if (i < 64 * 64) {
      int k = i >> 6, nn = i & 63;
      W2t[(size_t)nn * 64 + k] = f2bf(W2[i]);
    }
    return;
  }
  // AsAd2[2][64]
  {
    int i = tid;
    if (i < 128) {
      int o = i >> 6, k = i & 63;
      const float* att = (o == 0) ? att_s2 : att_d2;
      float s = 0.f;
      for (int c = 0; c < 64; c++) s += W2[(size_t)k * 64 + c] * att[c];
      AsAd2[i] = s;
    }
  }
}

// ======================================================================
// P2: block 0 = single-block scan; blocks 1.. = layer-1 attention dots.
// ======================================================================
__global__ __launch_bounds__(1024) void scan_dots(
    const int* __restrict__ counts, int* __restrict__ offsets,
    const unsigned short* __restrict__ xb, const unsigned short* __restrict__ AsAdT,
    float* __restrict__ asd, int n) {
  if (blockIdx.x == 0) {
    __shared__ int sums[1024];
    int t = threadIdx.x;
    int chunk = (n + 1023) >> 10;
    int start = t * chunk;
    int end = min(start + chunk, n);
    int s = 0;
    for (int i = start; i < end; i++) s += counts[i];
    sums[t] = s;
    __syncthreads();
    for (int off = 1; off < 1024; off <<= 1) {
      int v = (t >= off) ? sums[t - off] : 0;
      __syncthreads();
      sums[t] += v;
      __syncthreads();
    }
    int run = sums[t] - s;
    for (int i = start; i < end; i++) { offsets[i] = run; run += counts[i]; }
    if (t == 1023) offsets[n] = sums[1023];
    return;
  }
  int tid = threadIdx.x;
  int wave = tid >> 6, lane = tid & 63;
  int q = lane >> 4, t = lane & 15;
  int row0 = (blockIdx.x - 1) * 256 + wave * 16;
  int arow = row0 + t; if (arow > n - 1) arow = n - 1;
  const bf16x8* aptr = (const bf16x8*)(xb + (size_t)arow * 128);
  const bf16x8* bptr = (const bf16x8*)(AsAdT + t * 128);
  f32x4 acc = (f32x4){0.f, 0.f, 0.f, 0.f};
  #pragma unroll
  for (int s = 0; s < 4; s++)
    acc = __builtin_amdgcn_mfma_f32_16x16x32_bf16(aptr[s * 4 + q], bptr[s * 4 + q],
                                                  acc, 0, 0, 0);
  #pragma unroll
  for (int r = 0; r < 4; r++) {
    int row = row0 + q * 4 + r;
    if (row < n) asd[row * 16 + t] = acc[r];
  }
}

// ======================================================================
// P3: pure CSR fill (numerators computed inside agg kernels from asd).
// ======================================================================
__global__ __launch_bounds__(256) void fill_csr(
    const int* __restrict__ ei, const int* __restrict__ offsets,
    int* __restrict__ cursor, int* __restrict__ srcs, int E, int ET) {
  int i = blockIdx.x * 256 + threadIdx.x;
  if (i >= ET) return;
  int src, dst;
  if (i < E) { src = ei[i]; dst = ei[E + i]; } else { src = dst = i - E; }
  int pos = atomicAdd(&cursor[dst], 1);
  srcs[offsets[dst] + pos] = src;
}

// consume 8 staged 256B rows with readlane weight broadcasts
#define CONSUME8(STG, W, ACC)                                         \
  _Pragma("unroll")                                                   \
  for (int k = 0; k < 8; k++) {                                       \
    unsigned xv = *(const unsigned*)&(STG)[k * 128 + 2 * lane];       \
    f32x2 x2 = unpk(xv);                                              \
    ACC[0] += x2 * rlf(W, k * 8 + 0);                                 \
    ACC[1] += x2 * rlf(W, k * 8 + 1);                                 \
    ACC[2] += x2 * rlf(W, k * 8 + 2);                                 \
    ACC[3] += x2 * rlf(W, k * 8 + 3);                                 \
    ACC[4] += x2 * rlf(W, k * 8 + 4);                                 \
    ACC[5] += x2 * rlf(W, k * 8 + 5);                                 \
    ACC[6] += x2 * rlf(W, k * 8 + 6);                                 \
    ACC[7] += x2 * rlf(W, k * 8 + 7);                                 \
  }

// ======================================================================
// P4: fused layer-1 aggregation + GEMM + layer-2 dots.
// 16 nodes/block, 8 waves/block, TWO nodes per wave with interleaved
// independent chains: metadata for both issued together, all DMAs for
// both in flight, ONE vmcnt(0) drain per pair -> 2x memory-level
// parallelism per wave.  dma16 staging with padded rows (pads are
// cache-hot duplicates -- R3 showed they cost no fetch).
// ======================================================================
__global__ __launch_bounds__(512, 4) void agg1_gemm(
    const int* __restrict__ offsets, const int* __restrict__ srcs,
    const float* __restrict__ asd, const unsigned short* __restrict__ xb,
    const unsigned short* __restrict__ WbT, const float* __restrict__ b1,
    const float* __restrict__ AsAd2, unsigned short* __restrict__ zb,
    float* __restrict__ as2, float* __restrict__ ad2, int N) {
  // 16 node-slots x 4KB stage = 64 KiB; first 16*1032 ushorts reused as
  // the z-tile (stride 1032 keeps the MFMA reads conflict-free)
  __shared__ unsigned short sh[16 * 2048];
  int tid = threadIdx.x;
  int wv = tid >> 6, lane = tid & 63;   // wv in 0..7
  int nb = blockIdx.x;
  {
    int nodeA = nb * 16 + 2 * wv;       // wave owns nodes A and A+1
    unsigned short* stgA = &sh[(2 * wv) * 2048];
    unsigned short* stgB = &sh[(2 * wv + 1) * 2048];
    f32x2 accA[8], accB[8];
    #pragma unroll
    for (int h = 0; h < 8; h++) {
      accA[h] = (f32x2){0.f, 0.f};
      accB[h] = (f32x2){0.f, 0.f};
    }
    float wslA = 0.f, wslB = 0.f;
    int begA = offsets[nodeA];
    int endA = offsets[nodeA + 1];
    int endB = offsets[nodeA + 2];
    int begB = endA;
    int jlA = endA - 1, jlB = endB - 1;  // deg >= 1 (self-loop)
    float advA = asd[(size_t)nodeA * 16 + 8 + (lane & 7)];
    float advB = asd[(size_t)(nodeA + 1) * 16 + 8 + (lane & 7)];
    for (int c = 0;; c += 16) {
      int cbA = begA + c, cbB = begB + c;
      bool hA = cbA < endA, hB = cbB < endB;   // wave-uniform
      if (!hA && !hB) break;
      int cntA = endA - cbA, cntB = endB - cbB;
      // --- metadata: both nodes' loads issued together (independent) ---
      int sA0 = 0, sA1 = 0, sA2 = 0, sA3 = 0;
      int sB0 = 0, sB1 = 0, sB2 = 0, sB3 = 0;
      float asvaA = 0.f, asvbA = 0.f, asvaB = 0.f, asvbB = 0.f;
      if (hA) {
        sA0 = srcs[min(cbA + (lane >> 4), jlA)];
        sA1 = srcs[min(cbA + 4 + (lane >> 4), jlA)];
        int sw = srcs[min(cbA + (lane >> 3), jlA)];
        asvaA = asd[(size_t)sw * 16 + (lane & 7)];
        if (cntA > 8) {
          sA2 = srcs[min(cbA + 8 + (lane >> 4), jlA)];
          sA3 = srcs[min(cbA + 12 + (lane >> 4), jlA)];
          int sw2 = srcs[min(cbA + 8 + (lane >> 3), jlA)];
          asvbA = asd[(size_t)sw2 * 16 + (lane & 7)];
        }
      }
      if (hB) {
        sB0 = srcs[min(cbB + (lane >> 4), jlB)];
        sB1 = srcs[min(cbB + 4 + (lane >> 4), jlB)];
        int sw = srcs[min(cbB + (lane >> 3), jlB)];
        asvaB = asd[(size_t)sw * 16 + (lane & 7)];
        if (cntB > 8) {
          sB2 = srcs[min(cbB + 8 + (lane >> 4), jlB)];
          sB3 = srcs[min(cbB + 12 + (lane >> 4), jlB)];
          int sw2 = srcs[min(cbB + 8 + (lane >> 3), jlB)];
          asvbB = asd[(size_t)sw2 * 16 + (lane & 7)];
        }
      }
      // --- stage DMAs: all of A's and B's rows in flight together ---
      if (hA) {
        dma16(xb + (size_t)(unsigned)sA0 * 128 + (lane & 15) * 8, stgA);
        dma16(xb + (size_t)(unsigned)sA1 * 128 + (lane & 15) * 8, stgA + 512);
        if (cntA > 8) {
          dma16(xb + (size_t)(unsigned)sA2 * 128 + (lane & 15) * 8, stgA + 1024);
          dma16(xb + (size_t)(unsigned)sA3 * 128 + (lane & 15) * 8, stgA + 1536);
        }
      }
      if (hB) {
        dma16(xb + (size_t)(unsigned)sB0 * 128 + (lane & 15) * 8, stgB);
        dma16(xb + (size_t)(unsigned)sB1 * 128 + (lane & 15) * 8, stgB + 512);
        if (cntB > 8) {
          dma16(xb + (size_t)(unsigned)sB2 * 128 + (lane & 15) * 8, stgB + 1024);
          dma16(xb + (size_t)(unsigned)sB3 * 128 + (lane & 15) * 8, stgB + 1536);
        }
      }
      // --- weights (lane = edge*8+head layout), zero-padded ---
      float waA = 0.f, wbA = 0.f, waB = 0.f, wbB = 0.f;
      if (hA) {
        float v = asvaA + advA;
        v = (v > 0.f) ? v : NEG_SLOPE * v;
        waA = (cbA + (lane >> 3) < endA) ? __expf(v) : 0.f;
        if (cntA > 8) {
          v = asvbA + advA;
          v = (v > 0.f) ? v : NEG_SLOPE * v;
          wbA = (cbA + 8 + (lane >> 3) < endA) ? __expf(v) : 0.f;
        }
      }
      if (hB) {
        float v = asvaB + advB;
        v = (v > 0.f) ? v : NEG_SLOPE * v;
        waB = (cbB + (lane >> 3) < endB) ? __expf(v) : 0.f;
        if (cntB > 8) {
          v = asvbB + advB;
          v = (v > 0.f) ? v : NEG_SLOPE * v;
          wbB = (cbB + 8 + (lane >> 3) < endB) ? __expf(v) : 0.f;
        }
      }
      wslA += waA + wbA;
      wslB += waB + wbB;
      __builtin_amdgcn_s_waitcnt(0x0f70);   // vmcnt(0): all DMA rows landed
      if (hA) {
        CONSUME8(stgA, waA, accA);
        if (cntA > 8) { CONSUME8((stgA + 1024), wbA, accA); }
      }
      if (hB) {
        CONSUME8(stgB, waB, accB);
        if (cntB > 8) { CONSUME8((stgB + 1024), wbB, accB); }
      }
    }
    // denominators: sum the 8 lanes sharing (lane&7); lane h holds ws[h]
    wslA += __shfl_xor(wslA, 8, 64);
    wslA += __shfl_xor(wslA, 16, 64);
    wslA += __shfl_xor(wslA, 32, 64);
    wslB += __shfl_xor(wslB, 8, 64);
    wslB += __shfl_xor(wslB, 16, 64);
    wslB += __shfl_xor(wslB, 32, 64);
    __syncthreads();   // all waves done reading their stage regions
    #pragma unroll
    for (int h = 0; h < 8; h++) {
      float ivA = 0.125f / rlf(wslA, h);  // head-mean folded in
      unsigned oA = (unsigned)f2bf(accA[h].x * ivA) |
                    ((unsigned)f2bf(accA[h].y * ivA) << 16);
      *(unsigned*)&sh[(2 * wv) * 1032 + h * 128 + 2 * lane] = oA;
      float ivB = 0.125f / rlf(wslB, h);
      unsigned oB = (unsigned)f2bf(accB[h].x * ivB) |
                    ((unsigned)f2bf(accB[h].y * ivB) << 16);
      *(unsigned*)&sh[(2 * wv + 1) * 1032 + h * 128 + 2 * lane] = oB;
    }
  }
  __syncthreads();
  if (wv < 4) {
    int q = lane >> 4, t = lane & 15;
    f32x4 acc4 = (f32x4){0.f, 0.f, 0.f, 0.f};
    const unsigned short* bbase = WbT + (size_t)(wv * 16 + t) * 1024;
    #pragma unroll 8
    for (int s = 0; s < 32; s++) {
      bf16x8 af = *(const bf16x8*)&sh[t * 1032 + s * 32 + q * 8];
      bf16x8 bf = *(const bf16x8*)&bbase[s * 32 + q * 8];
      acc4 = __builtin_amdgcn_mfma_f32_16x16x32_bf16(af, bf, acc4, 0, 0, 0);
    }
    int col = wv * 16 + t;
    float bias = b1[col];
    float vs = AsAd2[col], vd = AsAd2[64 + col];
    #pragma unroll
    for (int r = 0; r < 4; r++) {
      int row = q * 4 + r;
      int node = nb * 16 + row;
      float v = acc4[r] + bias;
      v = (v > 0.f) ? v : (__expf(v) - 1.f);  // ELU
      zb[(size_t)node * 64 + col] = f2bf(v);
      float s = v * vs, d = v * vd;
      #pragma unroll
      for (int off = 1; off < 16; off <<= 1) {
        s += __shfl_xor(s, off, 64);
        d += __shfl_xor(d, off, 64);
      }
      if (t == 0) {
        atomicAdd(&as2[node], s);
        atomicAdd(&ad2[node], d);
      }
    }
  }
}

// ======================================================================
// P5: fused layer-2 aggregation + GEMM(W2) + bias -> out.
// Same 2-nodes-per-wave interleaved-chain structure; zb rows (128B)
// staged via dma16 (8 rows/inst, padded -- pads are cache-hot dups);
// one vmcnt(0) drain per node pair.  34KB LDS -> 4 blocks/CU.
// ======================================================================
__global__ __launch_bounds__(512, 8) void agg2_gemm(
    const int* __restrict__ offsets, const int* __restrict__ srcs,
    const float* __restrict__ as2, const float* __restrict__ ad2,
    const unsigned short* __restrict__ zb, const unsigned short* __restrict__ W2t,
    const float* __restrict__ b2, float* __restrict__ out, int N) {
  __shared__ unsigned short stg[16 * 1024];  // 16 node-slots x (16 edges x 128B)
  __shared__ unsigned short sh[16 * 72];
  int tid = threadIdx.x;
  int wv = tid >> 6, lane = tid & 63;   // wv in 0..7
  int nb = blockIdx.x;
  {
    int nodeA = nb * 16 + 2 * wv;
    unsigned short* stA = &stg[(2 * wv) * 1024];
    unsigned short* stB = &stg[(2 * wv + 1) * 1024];
    f32x2 accA = (f32x2){0.f, 0.f}, accB = (f32x2){0.f, 0.f};
    float wslA = 0.f, wslB = 0.f;
    int begA = offsets[nodeA];
    int endA = offsets[nodeA + 1];
    int endB = offsets[nodeA + 2];
    int begB = endA;
    int jlA = endA - 1, jlB = endB - 1;
    float advA = ad2[nodeA];
    float advB = ad2[nodeA + 1];
    for (int c = 0;; c += 16) {
      int cbA = begA + c, cbB = begB + c;
      bool hA = cbA < endA, hB = cbB < endB;
      if (!hA && !hB) break;
      int cntA = endA - cbA, cntB = endB - cbB;
      // metadata for both nodes issued together
      float wlA = 0.f, wlB = 0.f;
      int sR0A = 0, sR1A = 0, sR0B = 0, sR1B = 0;
      float asvA = 0.f, asvB = 0.f;
      if (hA) {
        int sAll = srcs[min(cbA + (lane & 15), jlA)];
        asvA = as2[sAll];
        sR0A = srcs[min(cbA + (lane >> 3), jlA)];
        if (cntA > 8) sR1A = srcs[min(cbA + 8 + (lane >> 3), jlA)];
      }
      if (hB) {
        int sAll = srcs[min(cbB + (lane & 15), jlB)];
        asvB = as2[sAll];
        sR0B = srcs[min(cbB + (lane >> 3), jlB)];
        if (cntB > 8) sR1B = srcs[min(cbB + 8 + (lane >> 3), jlB)];
      }
      // stage DMAs (8 zb rows per dma16)
      if (hA) {
        dma16(zb + (size_t)(unsigned)sR0A * 64 + (lane & 7) * 8, stA);
        if (cntA > 8)
          dma16(zb + (size_t)(unsigned)sR1A * 64 + (lane & 7) * 8, stA + 512);
      }
      if (hB) {
        dma16(zb + (size_t)(unsigned)sR0B * 64 + (lane & 7) * 8, stB);
        if (cntB > 8)
          dma16(zb + (size_t)(unsigned)sR1B * 64 + (lane & 7) * 8, stB + 512);
      }
      // weights (lane&15 = edge), zero-padded
      if (hA) {
        float v = asvA + advA;
        v = (v > 0.f) ? v : NEG_SLOPE * v;
        wlA = (cbA + (lane & 15) < endA) ? __expf(v) : 0.f;
      }
      if (hB) {
        float v = asvB + advB;
        v = (v > 0.f) ? v : NEG_SLOPE * v;
        wlB = (cbB + (lane & 15) < endB) ? __expf(v) : 0.f;
      }
      if (lane < 16) { wslA += wlA; wslB += wlB; }
      __builtin_amdgcn_s_waitcnt(0x0f70);    // vmcnt(0): rows landed
      // consume 2 edges/iter: lanes<32 -> even edge, lanes>=32 -> odd edge
      if (hA) {
        #pragma unroll
        for (int k = 0; k < 4; k++) {
          float w0 = rlf(wlA, 2 * k);
          float w1 = rlf(wlA, 2 * k + 1);
          float w = (lane >= 32) ? w1 : w0;
          unsigned zv = *(const unsigned*)&stA[k * 128 + 2 * lane];
          accA += unpk(zv) * w;
        }
        if (cntA > 8) {
          #pragma unroll
          for (int k = 4; k < 8; k++) {
            float w0 = rlf(wlA, 2 * k);
            float w1 = rlf(wlA, 2 * k + 1);
            float w = (lane >= 32) ? w1 : w0;
            unsigned zv = *(const unsigned*)&stA[k * 128 + 2 * lane];
            accA += unpk(zv) * w;
          }
        }
      }
      if (hB) {
        #pragma unroll
        for (int k = 0; k < 4; k++) {
          float w0 = rlf(wlB, 2 * k);
          float w1 = rlf(wlB, 2 * k + 1);
          float w = (lane >= 32) ? w1 : w0;
          unsigned zv = *(const unsigned*)&stB[k * 128 + 2 * lane];
          accB += unpk(zv) * w;
        }
        if (cntB > 8) {
          #pragma unroll
          for (int k = 4; k < 8; k++) {
            float w0 = rlf(wlB, 2 * k);
            float w1 = rlf(wlB, 2 * k + 1);
            float w = (lane >= 32) ? w1 : w0;
            unsigned zv = *(const unsigned*)&stB[k * 128 + 2 * lane];
            accB += unpk(zv) * w;
          }
        }
      }
    }
    // denominators (edges held in lanes 0-15)
    wslA += __shfl_xor(wslA, 1, 64);
    wslA += __shfl_xor(wslA, 2, 64);
    wslA += __shfl_xor(wslA, 4, 64);
    wslA += __shfl_xor(wslA, 8, 64);
    wslB += __shfl_xor(wslB, 1, 64);
    wslB += __shfl_xor(wslB, 2, 64);
    wslB += __shfl_xor(wslB, 4, 64);
    wslB += __shfl_xor(wslB, 8, 64);
    float totA = rlf(wslA, 0);
    float totB = rlf(wslB, 0);
    // fold odd-edge half into even half
    accA.x += __shfl_xor(accA.x, 32, 64);
    accA.y += __shfl_xor(accA.y, 32, 64);
    accB.x += __shfl_xor(accB.x, 32, 64);
    accB.y += __shfl_xor(accB.y, 32, 64);
    if (lane < 32) {
      float invA = 1.f / totA;
      unsigned oA = (unsigned)f2bf(accA.x * invA) |
                    ((unsigned)f2bf(accA.y * invA) << 16);
      *(unsigned*)&sh[(2 * wv) * 72 + 2 * lane] = oA;
      float invB = 1.f / totB;
      unsigned oB = (unsigned)f2bf(accB.x * invB) |
                    ((unsigned)f2bf(accB.y * invB) << 16);
      *(unsigned*)&sh[(2 * wv + 1) * 72 + 2 * lane] = oB;
    }
  }
  __syncthreads();
  if (wv < 4) {
    int q = lane >> 4, t = lane & 15;
    f32x4 acc4 = (f32x4){0.f, 0.f, 0.f, 0.f};
    const unsigned short* bbase = W2t + (size_t)(wv * 16 + t) * 64;
    #pragma unroll
    for (int s = 0; s < 2; s++) {
      bf16x8 af = *(const bf16x8*)&sh[t * 72 + s * 32 + q * 8];
      bf16x8 bf = *(const bf16x8*)&bbase[s * 32 + q * 8];
      acc4 = __builtin_amdgcn_mfma_f32_16x16x32_bf16(af, bf, acc4, 0, 0, 0);
    }
    int col = wv * 16 + t;
    float bias = b2[col];
    #pragma unroll
    for (int r = 0; r < 4; r++) {
      int node = nb * 16 + q * 4 + r;
      if (node < N) out[(size_t)node * 64 + col] = acc4[r] + bias;
    }
  }
}

// ---------- host launch ----------
extern "C" void kernel_launch(void* const* d_in, const int* in_sizes, int n_in,
                              void* d_out, int out_size, void* d_ws, size_t ws_size,
                              hipStream_t stream) {
  const int IN = 128;
  const int N = in_sizes[0] / IN;      // 50000
  const int E = in_sizes[1] / 2;       // 400000
  const int ET = E + N;

  const float* x        = (const float*)d_in[0];
  const int*   ei       = (const int*)d_in[1];
  const float* W1       = (const float*)d_in[2];
  const float* att_src1 = (const float*)d_in[3];
  const float* att_dst1 = (const float*)d_in[4];
  const float* b1       = (const float*)d_in[5];
  const float* W2       = (const float*)d_in[6];
  const float* att_src2 = (const float*)d_in[7];
  const float* att_dst2 = (const float*)d_in[8];
  const float* b2       = (const float*)d_in[9];
  float* out = (float*)d_out;

  char* base = (char*)d_ws;
  size_t off = 0;
  auto alloc = [&](size_t bytes) -> char* {
    char* p = base + off;
    off = (off + bytes + 255) & ~(size_t)255;
    return p;
  };
  unsigned short* xb    = (unsigned short*)alloc((size_t)N * 128 * 2);
  unsigned short* AsAdT = (unsigned short*)alloc((size_t)16 * 128 * 2);
  unsigned short* WbT   = (unsigned short*)alloc((size_t)64 * 1024 * 2);
  unsigned short* W2t   = (unsigned short*)alloc((size_t)64 * 64 * 2);
  unsigned short* zb    = (unsigned short*)alloc((size_t)N * 64 * 2);
  float* AsAd2 = (float*)alloc((size_t)128 * 4);
  float* asd1  = (float*)alloc((size_t)N * 16 * 4);
  int* offsets = (int*)alloc((size_t)(N + 1) * 4);
  int* srcs    = (int*)alloc((size_t)ET * 4);
  char* zero_begin = base + off;
  int* counts  = (int*)alloc((size_t)N * 4);
  int* cursor  = (int*)alloc((size_t)N * 4);
  float* a_s2  = (float*)alloc((size_t)N * 4);
  float* a_d2  = (float*)alloc((size_t)N * 4);
  char* zero_end = base + off;

  hipMemsetAsync(zero_begin, 0, (size_t)(zero_end - zero_begin), stream);

  const int TB = 256;
  auto cdiv = [](int a, int b) { return (a + b - 1) / b; };

  int B0 = cdiv(ET, TB);
  int B1 = cdiv(N * 32, TB);
  prep_all<<<B0 + B1 + 8 + 256 + 16 + 1, TB, 0, stream>>>(
      ei, counts, x, xb, W1, att_src1, att_dst1, AsAdT, WbT, W2, W2t,
      att_src2, att_dst2, AsAd2, E, ET, N, B0, B1);

  scan_dots<<<1 + cdiv(N, 256), 1024, 0, stream>>>(counts, offsets, xb, AsAdT,
                                                   asd1, N);

  fill_csr<<<cdiv(ET, TB), TB, 0, stream>>>(ei, offsets, cursor, srcs, E, ET);

  agg1_gemm<<<cdiv(N, 16), 512, 0, stream>>>(offsets, srcs, asd1, xb, WbT, b1,
                                             AsAd2, zb, a_s2, a_d2, N);

  agg2_gemm<<<cdiv(N, 16), 512, 0, stream>>>(offsets, srcs, a_s2, a_d2, zb,
                                             W2t, b2, out, N);
}

// Round 5
// 320.062 us; speedup vs baseline: 1.0863x; 1.0224x over previous
//
#include <hip/hip_runtime.h>
#include <cstdint>
#include <cstddef>

#define NEG_SLOPE 0.2f

typedef short bf16x8 __attribute__((ext_vector_type(8)));
typedef float f32x4 __attribute__((ext_vector_type(4)));
typedef float f32x2 __attribute__((ext_vector_type(2)));

__device__ __forceinline__ unsigned short f2bf(float f) {
  unsigned u = __float_as_uint(f);
  u = u + 0x7FFFu + ((u >> 16) & 1u);
  return (unsigned short)(u >> 16);
}
__device__ __forceinline__ float bf2f(unsigned short b) {
  return __uint_as_float((unsigned)b << 16);
}
__device__ __forceinline__ f32x2 unpk(unsigned xv) {
  f32x2 r;
  r.x = __uint_as_float(xv << 16);
  r.y = __uint_as_float(xv & 0xFFFF0000u);
  return r;
}
// wave-uniform broadcast of lane l's float (l compile-time or SGPR)
__device__ __forceinline__ float rlf(float v, int l) {
  return __uint_as_float(
      (unsigned)__builtin_amdgcn_readlane((int)__float_as_uint(v), l));
}

// ======================================================================
// P1: all independent prep, partitioned by blockIdx.
// ======================================================================
__global__ __launch_bounds__(256) void prep_all(
    const int* __restrict__ ei, int* __restrict__ counts,
    const float* __restrict__ x, unsigned short* __restrict__ xb,
    const float* __restrict__ W1, const float* __restrict__ att_s1,
    const float* __restrict__ att_d1, unsigned short* __restrict__ AsAdT,
    unsigned short* __restrict__ WbT,
    const float* __restrict__ W2, unsigned short* __restrict__ W2t,
    const float* __restrict__ att_s2, const float* __restrict__ att_d2,
    float* __restrict__ AsAd2,
    int E, int ET, int N, int B0, int B1) {
  int b = blockIdx.x, tid = threadIdx.x;
  if (b < B0) {  // count_dst
    int i = b * 256 + tid;
    if (i < ET) {
      int dst = (i < E) ? ei[E + i] : (i - E);
      atomicAdd(&counts[dst], 1);
    }
    return;
  }
  b -= B0;
  if (b < B1) {  // cast x -> xb
    int i = b * 256 + tid;
    if (i < N * 32) {
      float4 v = ((const float4*)x)[i];
      ushort4 o;
      o.x = f2bf(v.x); o.y = f2bf(v.y); o.z = f2bf(v.z); o.w = f2bf(v.w);
      ((ushort4*)xb)[i] = o;
    }
    return;
  }
  b -= B1;
  if (b < 8) {  // AsAdT[16][128]
    int i = b * 256 + tid;
    int o = i >> 7, k = i & 127, h = o & 7;
    const float* att = (o < 8) ? att_s1 : att_d1;
    float s = 0.f;
    for (int c = 0; c < 64; c++) s += W1[(size_t)k * 512 + h * 64 + c] * att[h * 64 + c];
    AsAdT[i] = f2bf(s);
    return;
  }
  b -= 8;
  if (b < 256) {  // WbT[64][1024]: WbT[o][h*128+c] = W1[c][h*64+o]
    int i = b * 256 + tid;
    int o = i >> 10, k = i & 1023, h = k >> 7, c = k & 127;
    WbT[i] = f2bf(W1[(size_t)c * 512 + h * 64 + o]);
    return;
  }
  b -= 256;
  if (b < 16) {  // W2t[64][64]: W2t[nn][k] = W2[k][nn]
    int i = b * 256 + tid;
    if (i < 64 * 64) {
      int k = i >> 6, nn = i & 63;
      W2t[(size_t)nn * 64 + k] = f2bf(W2[i]);
    }
    return;
  }
  // AsAd2[2][64]
  {
    int i = tid;
    if (i < 128) {
      int o = i >> 6, k = i & 63;
      const float* att = (o == 0) ? att_s2 : att_d2;
      float s = 0.f;
      for (int c = 0; c < 64; c++) s += W2[(size_t)k * 64 + c] * att[c];
      AsAd2[i] = s;
    }
  }
}

// ======================================================================
// P2: block 0 = single-block scan; blocks 1.. = layer-1 attention dots.
// ======================================================================
__global__ __launch_bounds__(1024) void scan_dots(
    const int* __restrict__ counts, int* __restrict__ offsets,
    const unsigned short* __restrict__ xb, const unsigned short* __restrict__ AsAdT,
    float* __restrict__ asd, int n) {
  if (blockIdx.x == 0) {
    __shared__ int sums[1024];
    int t = threadIdx.x;
    int chunk = (n + 1023) >> 10;
    int start = t * chunk;
    int end = min(start + chunk, n);
    int s = 0;
    for (int i = start; i < end; i++) s += counts[i];
    sums[t] = s;
    __syncthreads();
    for (int off = 1; off < 1024; off <<= 1) {
      int v = (t >= off) ? sums[t - off] : 0;
      __syncthreads();
      sums[t] += v;
      __syncthreads();
    }
    int run = sums[t] - s;
    for (int i = start; i < end; i++) { offsets[i] = run; run += counts[i]; }
    if (t == 1023) offsets[n] = sums[1023];
    return;
  }
  int tid = threadIdx.x;
  int wave = tid >> 6, lane = tid & 63;
  int q = lane >> 4, t = lane & 15;
  int row0 = (blockIdx.x - 1) * 256 + wave * 16;
  int arow = row0 + t; if (arow > n - 1) arow = n - 1;
  const bf16x8* aptr = (const bf16x8*)(xb + (size_t)arow * 128);
  const bf16x8* bptr = (const bf16x8*)(AsAdT + t * 128);
  f32x4 acc = (f32x4){0.f, 0.f, 0.f, 0.f};
  #pragma unroll
  for (int s = 0; s < 4; s++)
    acc = __builtin_amdgcn_mfma_f32_16x16x32_bf16(aptr[s * 4 + q], bptr[s * 4 + q],
                                                  acc, 0, 0, 0);
  #pragma unroll
  for (int r = 0; r < 4; r++) {
    int row = row0 + q * 4 + r;
    if (row < n) asd[row * 16 + t] = acc[r];
  }
}

// ======================================================================
// P3: pure CSR fill (numerators computed inside agg kernels from asd).
// ======================================================================
__global__ __launch_bounds__(256) void fill_csr(
    const int* __restrict__ ei, const int* __restrict__ offsets,
    int* __restrict__ cursor, int* __restrict__ srcs, int E, int ET) {
  int i = blockIdx.x * 256 + threadIdx.x;
  if (i >= ET) return;
  int src, dst;
  if (i < E) { src = ei[i]; dst = ei[E + i]; } else { src = dst = i - E; }
  int pos = atomicAdd(&cursor[dst], 1);
  srcs[offsets[dst] + pos] = src;
}

// consume 8 register rows with readlane weight broadcasts
#define CONSUME8R(RV, W, ACC)                                         \
  _Pragma("unroll")                                                   \
  for (int k = 0; k < 8; k++) {                                       \
    f32x2 x2 = unpk(RV[k]);                                           \
    ACC[0] += x2 * rlf(W, k * 8 + 0);                                 \
    ACC[1] += x2 * rlf(W, k * 8 + 1);                                 \
    ACC[2] += x2 * rlf(W, k * 8 + 2);                                 \
    ACC[3] += x2 * rlf(W, k * 8 + 3);                                 \
    ACC[4] += x2 * rlf(W, k * 8 + 4);                                 \
    ACC[5] += x2 * rlf(W, k * 8 + 5);                                 \
    ACC[6] += x2 * rlf(W, k * 8 + 6);                                 \
    ACC[7] += x2 * rlf(W, k * 8 + 7);                                 \
  }

// ======================================================================
// P4: fused layer-1 aggregation + GEMM + layer-2 dots.
// 16 nodes/block, 1024 threads, wave per node.  REGISTER gather: one
// coalesced global_load_dword per edge row (256B = 64 lanes x 4B)
// straight into the consume register -- no LDS stage, no vmcnt(0)
// drain, 16 loads in flight per wave.  LDS = z-tile only (33 KB) so
// occupancy returns to the 32-wave/CU cap.
// ======================================================================
__global__ __launch_bounds__(1024, 8) void agg1_gemm(
    const int* __restrict__ offsets, const int* __restrict__ srcs,
    const float* __restrict__ asd, const unsigned short* __restrict__ xb,
    const unsigned short* __restrict__ WbT, const float* __restrict__ b1,
    const float* __restrict__ AsAd2, unsigned short* __restrict__ zb,
    float* __restrict__ as2, float* __restrict__ ad2, int N) {
  __shared__ unsigned short sh[16 * 1032];  // z-tile, stride 1032 (conflict-free)
  int tid = threadIdx.x;
  int wv = tid >> 6, lane = tid & 63;
  int nb = blockIdx.x;
  {
    int node = nb * 16 + wv;
    f32x2 acc[8];
    #pragma unroll
    for (int h = 0; h < 8; h++) acc[h] = (f32x2){0.f, 0.f};
    float wsl = 0.f;
    int beg = offsets[node], end = offsets[node + 1];
    int jl = end - 1;                       // deg >= 1 (self-loop)
    float adv = asd[(size_t)node * 16 + 8 + (lane & 7)];  // dst dots
    for (int cb = beg; cb < end; cb += 16) {
      int cnt = min(16, end - cb);
      // per-chunk metadata: lane&15 = edge id (feeds readlane row bcast)
      int sAll = srcs[min(cb + (lane & 15), jl)];
      int swa = srcs[min(cb + (lane >> 3), jl)];
      float asva = asd[(size_t)swa * 16 + (lane & 7)];
      float asvb = 0.f;
      if (cnt > 8) {
        int swb = srcs[min(cb + 8 + (lane >> 3), jl)];
        asvb = asd[(size_t)swb * 16 + (lane & 7)];
      }
      // register gather: one coalesced dword per edge row, all in flight
      unsigned rva[8], rvb[8];
      #pragma unroll
      for (int k = 0; k < 8; k++) {
        int se = __builtin_amdgcn_readlane(sAll, k);
        rva[k] = *(const unsigned*)&xb[(size_t)(unsigned)se * 128 + 2 * lane];
      }
      if (cnt > 8) {
        #pragma unroll
        for (int k = 0; k < 8; k++) {
          int se = __builtin_amdgcn_readlane(sAll, k + 8);
          rvb[k] = *(const unsigned*)&xb[(size_t)(unsigned)se * 128 + 2 * lane];
        }
      }
      // weights (lane = edge*8+head layout), zero-padded
      float wa, wb = 0.f;
      {
        float v = asva + adv;
        v = (v > 0.f) ? v : NEG_SLOPE * v;
        wa = (cb + (lane >> 3) < end) ? __expf(v) : 0.f;
      }
      if (cnt > 8) {
        float v = asvb + adv;
        v = (v > 0.f) ? v : NEG_SLOPE * v;
        wb = (cb + 8 + (lane >> 3) < end) ? __expf(v) : 0.f;
      }
      wsl += wa + wb;                       // per-lane denominator partial
      CONSUME8R(rva, wa, acc);
      if (cnt > 8) { CONSUME8R(rvb, wb, acc); }
    }
    // denominator: sum the 8 lanes sharing (lane&7); lane h holds ws[h]
    wsl += __shfl_xor(wsl, 8, 64);
    wsl += __shfl_xor(wsl, 16, 64);
    wsl += __shfl_xor(wsl, 32, 64);
    #pragma unroll
    for (int h = 0; h < 8; h++) {
      float tot = rlf(wsl, h);
      float iv = 0.125f / tot;  // head-mean folded in
      unsigned o = (unsigned)f2bf(acc[h].x * iv) | ((unsigned)f2bf(acc[h].y * iv) << 16);
      *(unsigned*)&sh[wv * 1032 + h * 128 + 2 * lane] = o;
    }
  }
  __syncthreads();
  if (wv < 4) {
    int q = lane >> 4, t = lane & 15;
    f32x4 acc4 = (f32x4){0.f, 0.f, 0.f, 0.f};
    const unsigned short* bbase = WbT + (size_t)(wv * 16 + t) * 1024;
    #pragma unroll 8
    for (int s = 0; s < 32; s++) {
      bf16x8 af = *(const bf16x8*)&sh[t * 1032 + s * 32 + q * 8];
      bf16x8 bf = *(const bf16x8*)&bbase[s * 32 + q * 8];
      acc4 = __builtin_amdgcn_mfma_f32_16x16x32_bf16(af, bf, acc4, 0, 0, 0);
    }
    int col = wv * 16 + t;
    float bias = b1[col];
    float vs = AsAd2[col], vd = AsAd2[64 + col];
    #pragma unroll
    for (int r = 0; r < 4; r++) {
      int row = q * 4 + r;
      int node = nb * 16 + row;
      float v = acc4[r] + bias;
      v = (v > 0.f) ? v : (__expf(v) - 1.f);  // ELU
      zb[(size_t)node * 64 + col] = f2bf(v);
      float s = v * vs, d = v * vd;
      #pragma unroll
      for (int off = 1; off < 16; off <<= 1) {
        s += __shfl_xor(s, off, 64);
        d += __shfl_xor(d, off, 64);
      }
      if (t == 0) {
        atomicAdd(&as2[node], s);
        atomicAdd(&ad2[node], d);
      }
    }
  }
}

// ======================================================================
// P5: fused layer-2 aggregation + GEMM(W2) + bias -> out.
// Same register-gather structure: zb row = 128B = 32 lanes x 4B, two
// rows per coalesced load (lane>>5 selects row), 8 loads per 16-edge
// chunk, no LDS stage.  LDS = 2.3 KB -> occupancy at wave-slot cap.
// ======================================================================
__global__ __launch_bounds__(1024, 8) void agg2_gemm(
    const int* __restrict__ offsets, const int* __restrict__ srcs,
    const float* __restrict__ as2, const float* __restrict__ ad2,
    const unsigned short* __restrict__ zb, const unsigned short* __restrict__ W2t,
    const float* __restrict__ b2, float* __restrict__ out, int N) {
  __shared__ unsigned short sh[16 * 72];
  int tid = threadIdx.x;
  int wv = tid >> 6, lane = tid & 63;
  int nb = blockIdx.x;
  {
    int node = nb * 16 + wv;
    int half = lane >> 5;                   // 0: even edges, 1: odd edges
    float adv = ad2[node];
    int beg = offsets[node], end = offsets[node + 1];
    int jl = end - 1;                        // deg >= 1 (self-loop)
    f32x2 acc = (f32x2){0.f, 0.f};
    float wsl = 0.f;
    for (int cb = beg; cb < end; cb += 16) {
      int cnt = min(16, end - cb);
      int sAll = srcs[min(cb + (lane & 15), jl)];
      float asv = as2[sAll];                 // weight source (lane&15 = edge)
      // register gather: 2 zb rows per coalesced load
      unsigned rv[8];
      #pragma unroll
      for (int k = 0; k < 4; k++) {
        int s0 = __builtin_amdgcn_readlane(sAll, 2 * k);
        int s1 = __builtin_amdgcn_readlane(sAll, 2 * k + 1);
        int se = half ? s1 : s0;
        rv[k] = *(const unsigned*)&zb[(size_t)(unsigned)se * 64 + 2 * (lane & 31)];
      }
      if (cnt > 8) {
        #pragma unroll
        for (int k = 4; k < 8; k++) {
          int s0 = __builtin_amdgcn_readlane(sAll, 2 * k);
          int s1 = __builtin_amdgcn_readlane(sAll, 2 * k + 1);
          int se = half ? s1 : s0;
          rv[k] = *(const unsigned*)&zb[(size_t)(unsigned)se * 64 + 2 * (lane & 31)];
        }
      }
      float v = asv + adv;
      v = (v > 0.f) ? v : NEG_SLOPE * v;
      float wl = (cb + (lane & 15) < end) ? __expf(v) : 0.f;
      if (lane < 16) wsl += wl;              // each edge counted once
      #pragma unroll
      for (int k = 0; k < 4; k++) {
        float w0 = rlf(wl, 2 * k);
        float w1 = rlf(wl, 2 * k + 1);
        float w = half ? w1 : w0;
        acc += unpk(rv[k]) * w;
      }
      if (cnt > 8) {
        #pragma unroll
        for (int k = 4; k < 8; k++) {
          float w0 = rlf(wl, 2 * k);
          float w1 = rlf(wl, 2 * k + 1);
          float w = half ? w1 : w0;
          acc += unpk(rv[k]) * w;
        }
      }
    }
    // denominator: total over edges (held in lanes 0-15)
    wsl += __shfl_xor(wsl, 1, 64);
    wsl += __shfl_xor(wsl, 2, 64);
    wsl += __shfl_xor(wsl, 4, 64);
    wsl += __shfl_xor(wsl, 8, 64);
    float tot = rlf(wsl, 0);
    // fold odd-edge half into even half
    acc.x += __shfl_xor(acc.x, 32, 64);
    acc.y += __shfl_xor(acc.y, 32, 64);
    if (lane < 32) {
      float inv = 1.f / tot;
      unsigned o = (unsigned)f2bf(acc.x * inv) | ((unsigned)f2bf(acc.y * inv) << 16);
      *(unsigned*)&sh[wv * 72 + 2 * lane] = o;
    }
  }
  __syncthreads();
  if (wv < 4) {
    int q = lane >> 4, t = lane & 15;
    f32x4 acc4 = (f32x4){0.f, 0.f, 0.f, 0.f};
    const unsigned short* bbase = W2t + (size_t)(wv * 16 + t) * 64;
    #pragma unroll
    for (int s = 0; s < 2; s++) {
      bf16x8 af = *(const bf16x8*)&sh[t * 72 + s * 32 + q * 8];
      bf16x8 bf = *(const bf16x8*)&bbase[s * 32 + q * 8];
      acc4 = __builtin_amdgcn_mfma_f32_16x16x32_bf16(af, bf, acc4, 0, 0, 0);
    }
    int col = wv * 16 + t;
    float bias = b2[col];
    #pragma unroll
    for (int r = 0; r < 4; r++) {
      int node = nb * 16 + q * 4 + r;
      if (node < N) out[(size_t)node * 64 + col] = acc4[r] + bias;
    }
  }
}

// ---------- host launch ----------
extern "C" void kernel_launch(void* const* d_in, const int* in_sizes, int n_in,
                              void* d_out, int out_size, void* d_ws, size_t ws_size,
                              hipStream_t stream) {
  const int IN = 128;
  const int N = in_sizes[0] / IN;      // 50000
  const int E = in_sizes[1] / 2;       // 400000
  const int ET = E + N;

  const float* x        = (const float*)d_in[0];
  const int*   ei       = (const int*)d_in[1];
  const float* W1       = (const float*)d_in[2];
  const float* att_src1 = (const float*)d_in[3];
  const float* att_dst1 = (const float*)d_in[4];
  const float* b1       = (const float*)d_in[5];
  const float* W2       = (const float*)d_in[6];
  const float* att_src2 = (const float*)d_in[7];
  const float* att_dst2 = (const float*)d_in[8];
  const float* b2       = (const float*)d_in[9];
  float* out = (float*)d_out;

  char* base = (char*)d_ws;
  size_t off = 0;
  auto alloc = [&](size_t bytes) -> char* {
    char* p = base + off;
    off = (off + bytes + 255) & ~(size_t)255;
    return p;
  };
  unsigned short* xb    = (unsigned short*)alloc((size_t)N * 128 * 2);
  unsigned short* AsAdT = (unsigned short*)alloc((size_t)16 * 128 * 2);
  unsigned short* WbT   = (unsigned short*)alloc((size_t)64 * 1024 * 2);
  unsigned short* W2t   = (unsigned short*)alloc((size_t)64 * 64 * 2);
  unsigned short* zb    = (unsigned short*)alloc((size_t)N * 64 * 2);
  float* AsAd2 = (float*)alloc((size_t)128 * 4);
  float* asd1  = (float*)alloc((size_t)N * 16 * 4);
  int* offsets = (int*)alloc((size_t)(N + 1) * 4);
  int* srcs    = (int*)alloc((size_t)ET * 4);
  char* zero_begin = base + off;
  int* counts  = (int*)alloc((size_t)N * 4);
  int* cursor  = (int*)alloc((size_t)N * 4);
  float* a_s2  = (float*)alloc((size_t)N * 4);
  float* a_d2  = (float*)alloc((size_t)N * 4);
  char* zero_end = base + off;

  hipMemsetAsync(zero_begin, 0, (size_t)(zero_end - zero_begin), stream);

  const int TB = 256;
  auto cdiv = [](int a, int b) { return (a + b - 1) / b; };

  int B0 = cdiv(ET, TB);
  int B1 = cdiv(N * 32, TB);
  prep_all<<<B0 + B1 + 8 + 256 + 16 + 1, TB, 0, stream>>>(
      ei, counts, x, xb, W1, att_src1, att_dst1, AsAdT, WbT, W2, W2t,
      att_src2, att_dst2, AsAd2, E, ET, N, B0, B1);

  scan_dots<<<1 + cdiv(N, 256), 1024, 0, stream>>>(counts, offsets, xb, AsAdT,
                                                   asd1, N);

  fill_csr<<<cdiv(ET, TB), TB, 0, stream>>>(ei, offsets, cursor, srcs, E, ET);

  agg1_gemm<<<cdiv(N, 16), 1024, 0, stream>>>(offsets, srcs, asd1, xb, WbT, b1,
                                              AsAd2, zb, a_s2, a_d2, N);

  agg2_gemm<<<cdiv(N, 16), 1024, 0, stream>>>(offsets, srcs, a_s2, a_d2, zb,
                                              W2t, b2, out, N);
}